// Round 1
// baseline (197.643 us; speedup 1.0000x reference)
//
#include <hip/hip_runtime.h>
#include <hip/hip_bf16.h>

// Problem sizes (fixed by reference)
#define B_   4
#define T_   2048
#define D_   512
#define H_   8
#define DH_  64
#define BT_  (B_*T_)          // 8192
#define N3D_ (3*D_)           // 1536

typedef __bf16  bf16x8 __attribute__((ext_vector_type(8)));
typedef float   f32x4  __attribute__((ext_vector_type(4)));
typedef short   short8 __attribute__((ext_vector_type(8)));
typedef unsigned short u16;

static __device__ __forceinline__ f32x4 fzero() { f32x4 z = {0.f,0.f,0.f,0.f}; return z; }

static __device__ __forceinline__ f32x4 mfma16(short8 a, short8 b, f32x4 c) {
  return __builtin_amdgcn_mfma_f32_16x16x32_bf16(
      __builtin_bit_cast(bf16x8, a), __builtin_bit_cast(bf16x8, b), c, 0, 0, 0);
}

// XOR swizzle for [row][128B] LDS tiles: applied identically on write and read,
// so it is correctness-neutral (bijective within each row) and kills the
// 16-lane row-stride-128B bank conflict (guide §6 G4).
static __device__ __forceinline__ int swz(int byteoff) {
  return byteoff ^ (((byteoff >> 7) & 7) << 4);
}

static __device__ __forceinline__ u16 bf16bits(float f) {
  __hip_bfloat16 h = __float2bfloat16(f);
  return *reinterpret_cast<u16*>(&h);
}

// ---------------------------------------------------------------------------
// Kernel 1: convert x -> bf16; transpose weights to (N,K) bf16 layout.
// ---------------------------------------------------------------------------
__global__ __launch_bounds__(256) void prep_kernel(
    const float* __restrict__ x, const float* __restrict__ wqkv,
    const float* __restrict__ wout,
    u16* __restrict__ xb, u16* __restrict__ wqkvT, u16* __restrict__ woutT) {
  int i = blockIdx.x * blockDim.x + threadIdx.x;
  int n = gridDim.x * blockDim.x;
  for (int idx = i; idx < BT_*D_; idx += n)
    xb[idx] = bf16bits(x[idx]);
  for (int idx = i; idx < N3D_*D_; idx += n) {
    int nn = idx >> 9, kk = idx & 511;
    wqkvT[idx] = bf16bits(wqkv[kk * N3D_ + nn]);
  }
  for (int idx = i; idx < D_*D_; idx += n) {
    int nn = idx >> 9, kk = idx & 511;
    woutT[idx] = bf16bits(wout[kk * D_ + nn]);
  }
}

// ---------------------------------------------------------------------------
// GEMM: C[M=8192][N] = A[M][512] * Wt[N][512]^T  (both bf16, K=512, BK=64)
// 128x128 tile, 4 waves, each wave owns a 64x64 quadrant = 4x4 MFMA frags.
// MODE 0: N=1536, epilogue scatters into q (scaled 1/8), k, v^T bf16 buffers.
// MODE 1: N=512,  epilogue adds bias, multiplies row mask, stores f32.
// ---------------------------------------------------------------------------
template <int MODE>
__global__ __launch_bounds__(256) void gemm_kernel(
    const u16* __restrict__ A, const u16* __restrict__ Wt,
    u16* __restrict__ qbuf, u16* __restrict__ kbuf, u16* __restrict__ vtbuf,
    const float* __restrict__ bias, const float* __restrict__ msk,
    float* __restrict__ out) {
  const int bn = blockIdx.x, bm = blockIdx.y;
  const int tid = threadIdx.x;
  const int w = tid >> 6, l = tid & 63;
  const int wr = w >> 1, wc = w & 1;
  const int lr = l & 15, lg = l >> 4;

  __shared__ char lsA[128 * 128];   // [128 rows][64 bf16]
  __shared__ char lsB[128 * 128];

  f32x4 acc[4][4];
#pragma unroll
  for (int i = 0; i < 4; ++i)
#pragma unroll
    for (int j = 0; j < 4; ++j) acc[i][j] = fzero();

  const long arow0 = (long)bm * 128;
  const long brow0 = (long)bn * 128;
  const char* Ab  = reinterpret_cast<const char*>(A);
  const char* Wb  = reinterpret_cast<const char*>(Wt);

  for (int kt = 0; kt < 8; ++kt) {
    // stage 128x64 bf16 tiles of A and Wt (reg-staged, swizzled LDS writes)
#pragma unroll
    for (int s = 0; s < 4; ++s) {
      int u = tid + s * 256;          // 0..1023, 16B units
      int row = u >> 3;
      int cb = (u & 7) << 4;          // byte col within 128B row
      short8 va = *reinterpret_cast<const short8*>(
          Ab + (arow0 + row) * 1024 + kt * 128 + cb);
      *reinterpret_cast<short8*>(lsA + swz(row * 128 + cb)) = va;
      short8 vb = *reinterpret_cast<const short8*>(
          Wb + (brow0 + row) * 1024 + kt * 128 + cb);
      *reinterpret_cast<short8*>(lsB + swz(row * 128 + cb)) = vb;
    }
    __syncthreads();

#pragma unroll
    for (int c = 0; c < 2; ++c) {
      short8 af[4], bfr[4];
#pragma unroll
      for (int mi = 0; mi < 4; ++mi) {
        int row = wr * 64 + mi * 16 + lr;
        af[mi] = *reinterpret_cast<const short8*>(
            lsA + swz(row * 128 + c * 64 + lg * 16));
      }
#pragma unroll
      for (int ni = 0; ni < 4; ++ni) {
        int row = wc * 64 + ni * 16 + lr;
        bfr[ni] = *reinterpret_cast<const short8*>(
            lsB + swz(row * 128 + c * 64 + lg * 16));
      }
#pragma unroll
      for (int mi = 0; mi < 4; ++mi)
#pragma unroll
        for (int ni = 0; ni < 4; ++ni)
          acc[mi][ni] = mfma16(af[mi], bfr[ni], acc[mi][ni]);
    }
    __syncthreads();
  }

  // epilogue: D-frag mapping col=lane&15, row=(lane>>4)*4+reg
#pragma unroll
  for (int mi = 0; mi < 4; ++mi) {
#pragma unroll
    for (int r = 0; r < 4; ++r) {
      int grow = bm * 128 + wr * 64 + mi * 16 + lg * 4 + r;
#pragma unroll
      for (int ni = 0; ni < 4; ++ni) {
        int gcol = bn * 128 + wc * 64 + ni * 16 + lr;
        float v = acc[mi][ni][r];
        if (MODE == 0) {
          int b = grow >> 11, t = grow & (T_ - 1);
          int which = gcol >> 9, w512 = gcol & 511;
          int h = w512 >> 6, d = w512 & 63;
          long bh = (long)(b * H_ + h);
          if (which == 0)       qbuf[(bh * T_ + t) * DH_ + d] = bf16bits(v * 0.125f);
          else if (which == 1)  kbuf[(bh * T_ + t) * DH_ + d] = bf16bits(v);
          else                  vtbuf[(bh * DH_ + d) * T_ + t] = bf16bits(v);
        } else {
          float o = (v + bias[gcol]) * msk[grow];
          out[(long)grow * D_ + gcol] = o;
        }
      }
    }
  }
}

// ---------------------------------------------------------------------------
// Flash attention: grid (T/64, B*H). 4 waves/block, 16 q-rows per wave.
// Q pre-scaled by 1/8 in GEMM1. K tile (64x64) and V^T tile (64x64) staged in
// swizzled LDS. P goes through a per-wave LDS round-trip (D-layout -> A-layout).
// ---------------------------------------------------------------------------
__global__ __launch_bounds__(256) void attn_kernel(
    const u16* __restrict__ q, const u16* __restrict__ k,
    const u16* __restrict__ vt, const float* __restrict__ msk,
    u16* __restrict__ ao) {
  const int qt = blockIdx.x;       // 0..31
  const int bh = blockIdx.y;       // 0..31
  const int b = bh >> 3, h = bh & 7;
  const int tid = threadIdx.x;
  const int w = tid >> 6, l = tid & 63;
  const int lr = l & 15, lg = l >> 4;

  __shared__ char lsK[64 * 128];
  __shared__ char lsV[64 * 128];
  __shared__ char lsP[4 * 16 * 128];
  char* pbase = lsP + w * (16 * 128);

  const char* qb = reinterpret_cast<const char*>(q);
  const char* kb = reinterpret_cast<const char*>(k);
  const char* vb = reinterpret_cast<const char*>(vt);

  const int qrow0 = qt * 64 + w * 16;

  // hoist Q fragments (2 k-chunks over DH=64)
  short8 qf[2];
#pragma unroll
  for (int c = 0; c < 2; ++c)
    qf[c] = *reinterpret_cast<const short8*>(
        qb + (((long)bh * T_ + qrow0 + lr) * DH_ + c * 32 + lg * 8) * 2);

  float mrun[4], lrun[4];
  f32x4 oacc[4];
#pragma unroll
  for (int r = 0; r < 4; ++r) { mrun[r] = -__builtin_inff(); lrun[r] = 0.f; }
#pragma unroll
  for (int g = 0; g < 4; ++g) oacc[g] = fzero();

  for (int kt = 0; kt <= qt; ++kt) {
    // stage K (64 kv-rows x 64 d) and V^T (64 d-rows x 64 kv)
#pragma unroll
    for (int s = 0; s < 2; ++s) {
      int u = tid + s * 256;        // 0..511 16B units
      int row = u >> 3;
      int cb = (u & 7) << 4;
      short8 vk = *reinterpret_cast<const short8*>(
          kb + ((long)bh * T_ + kt * 64 + row) * 128 + cb);
      *reinterpret_cast<short8*>(lsK + swz(row * 128 + cb)) = vk;
      short8 vv = *reinterpret_cast<const short8*>(
          vb + ((long)bh * DH_ + row) * (T_ * 2) + kt * 128 + cb);
      *reinterpret_cast<short8*>(lsV + swz(row * 128 + cb)) = vv;
    }
    __syncthreads();

    // scores S = Q K^T (already scaled): 4 n-tiles x 2 k-chunks
    f32x4 sc[4];
#pragma unroll
    for (int ni = 0; ni < 4; ++ni) {
      int row = ni * 16 + lr;
      short8 kb0 = *reinterpret_cast<const short8*>(lsK + swz(row * 128 + 0 + lg * 16));
      short8 kb1 = *reinterpret_cast<const short8*>(lsK + swz(row * 128 + 64 + lg * 16));
      f32x4 z = fzero();
      z = mfma16(qf[0], kb0, z);
      z = mfma16(qf[1], kb1, z);
      sc[ni] = z;
    }

    // mask: causal + key padding (finite -FLT_MAX like the reference)
#pragma unroll
    for (int ni = 0; ni < 4; ++ni) {
      int jcol = kt * 64 + ni * 16 + lr;
      float mj = msk[b * T_ + jcol];
      bool colbad = (mj == 0.f);
#pragma unroll
      for (int r = 0; r < 4; ++r) {
        int qi = qrow0 + lg * 4 + r;
        if (colbad || jcol > qi) sc[ni][r] = -3.402823466e38f;
      }
    }

    // online softmax (rows live in 16-lane groups; reduce with width-16 shfl)
    float pv[4][4];
#pragma unroll
    for (int r = 0; r < 4; ++r) {
      float mx = fmaxf(fmaxf(sc[0][r], sc[1][r]), fmaxf(sc[2][r], sc[3][r]));
#pragma unroll
      for (int o = 8; o >= 1; o >>= 1) mx = fmaxf(mx, __shfl_xor(mx, o, 16));
      float newm = fmaxf(mrun[r], mx);
      float alpha = __expf(mrun[r] - newm);
      float rs = 0.f;
#pragma unroll
      for (int ni = 0; ni < 4; ++ni) {
        float p = __expf(sc[ni][r] - newm);
        pv[ni][r] = p;
        rs += p;
      }
#pragma unroll
      for (int o = 8; o >= 1; o >>= 1) rs += __shfl_xor(rs, o, 16);
      lrun[r] = lrun[r] * alpha + rs;
      mrun[r] = newm;
#pragma unroll
      for (int g = 0; g < 4; ++g) oacc[g][r] *= alpha;
    }

    // P (D-layout) -> per-wave LDS (bf16) -> A-layout fragments
#pragma unroll
    for (int ni = 0; ni < 4; ++ni)
#pragma unroll
      for (int r = 0; r < 4; ++r) {
        int row = lg * 4 + r;
        int col = ni * 16 + lr;
        *reinterpret_cast<u16*>(pbase + swz(row * 128 + col * 2)) =
            bf16bits(pv[ni][r]);
      }
    asm volatile("s_waitcnt lgkmcnt(0)" ::: "memory");

    // O += P V : A from P-lds, B from V^T-lds
#pragma unroll
    for (int c = 0; c < 2; ++c) {
      short8 pa = *reinterpret_cast<const short8*>(
          pbase + swz(lr * 128 + c * 64 + lg * 16));
#pragma unroll
      for (int g = 0; g < 4; ++g) {
        int row = g * 16 + lr;
        short8 vf = *reinterpret_cast<const short8*>(
            lsV + swz(row * 128 + c * 64 + lg * 16));
        oacc[g] = mfma16(pa, vf, oacc[g]);
      }
    }
    __syncthreads();
  }

  // finalize and store attention output (bf16, (B,T,D) layout)
#pragma unroll
  for (int g = 0; g < 4; ++g)
#pragma unroll
    for (int r = 0; r < 4; ++r) {
      int t = qrow0 + lg * 4 + r;
      int col = h * 64 + g * 16 + lr;
      float v = oacc[g][r] / lrun[r];
      ao[((long)(b * T_ + t)) * D_ + col] = bf16bits(v);
    }
}

// ---------------------------------------------------------------------------
extern "C" void kernel_launch(void* const* d_in, const int* in_sizes, int n_in,
                              void* d_out, int out_size, void* d_ws,
                              size_t ws_size, hipStream_t stream) {
  const float* x    = (const float*)d_in[0];
  const float* msk  = (const float*)d_in[1];   // (B,T,1)
  const float* wqkv = (const float*)d_in[2];   // (512,1536)
  const float* wout = (const float*)d_in[3];   // (512,512)
  const float* bout = (const float*)d_in[4];   // (512,)
  float* out = (float*)d_out;

  char* ws = (char*)d_ws;
  u16* xb    = (u16*)(ws);                     //  8 MB  x bf16 (8192,512)
  u16* wqkvT = (u16*)(ws + 8388608);           //  1.5MB (1536,512)
  u16* woutT = (u16*)(ws + 9961472);           //  0.5MB (512,512)
  u16* qbuf  = (u16*)(ws + 10485760);          //  8 MB  (B,H,T,DH) scaled
  u16* kbuf  = (u16*)(ws + 18874368);          //  8 MB  (B,H,T,DH)
  u16* vtbuf = (u16*)(ws + 27262976);          //  8 MB  (B,H,DH,T)
  u16* ao    = (u16*)(ws + 35651584);          //  8 MB  (B,T,D)

  prep_kernel<<<1024, 256, 0, stream>>>(x, wqkv, wout, xb, wqkvT, woutT);
  gemm_kernel<0><<<dim3(N3D_ / 128, BT_ / 128), 256, 0, stream>>>(
      xb, wqkvT, qbuf, kbuf, vtbuf, nullptr, nullptr, nullptr);
  attn_kernel<<<dim3(T_ / 64, B_ * H_), 256, 0, stream>>>(
      qbuf, kbuf, vtbuf, msk, ao);
  gemm_kernel<1><<<dim3(D_ / 128, BT_ / 128), 256, 0, stream>>>(
      ao, woutT, nullptr, nullptr, nullptr, bout, msk, out);
}

// Round 2
// 106.835 us; speedup vs baseline: 1.8500x; 1.8500x over previous
//
#include <hip/hip_runtime.h>
#include <hip/hip_bf16.h>

// Problem sizes (fixed by reference)
#define B_   4
#define T_   2048
#define D_   512
#define H_   8
#define DH_  64
#define BT_  (B_*T_)          // 8192
#define N3D_ (3*D_)           // 1536

typedef __bf16  bf16x8 __attribute__((ext_vector_type(8)));
typedef float   f32x4  __attribute__((ext_vector_type(4)));
typedef short   short8 __attribute__((ext_vector_type(8)));
typedef unsigned short u16;

// exp2 fast path: fold log2(e) into the Q scale so softmax uses v_exp_f32
// (which is natively 2^x) with no per-element multiply.
#if defined(__has_builtin)
#if __has_builtin(__builtin_amdgcn_exp2f)
#define EXP2_OK 1
#endif
#endif
#ifndef EXP2_OK
#define EXP2_OK 0
#endif

#if EXP2_OK
#define QSCALE_F (0.125f * 1.44269504088896340736f)
static __device__ __forceinline__ float fastexp(float x) { return __builtin_amdgcn_exp2f(x); }
#else
#define QSCALE_F (0.125f)
static __device__ __forceinline__ float fastexp(float x) { return __expf(x); }
#endif

static __device__ __forceinline__ f32x4 fzero() { f32x4 z = {0.f,0.f,0.f,0.f}; return z; }

static __device__ __forceinline__ f32x4 mfma16(short8 a, short8 b, f32x4 c) {
  return __builtin_amdgcn_mfma_f32_16x16x32_bf16(
      __builtin_bit_cast(bf16x8, a), __builtin_bit_cast(bf16x8, b), c, 0, 0, 0);
}

// XOR swizzle for [row][128B] LDS tiles: applied identically on write and read,
// bijective within each 8-row stripe (guide §6 G4).
static __device__ __forceinline__ int swz(int byteoff) {
  return byteoff ^ (((byteoff >> 7) & 7) << 4);
}

static __device__ __forceinline__ u16 bf16bits(float f) {
  __hip_bfloat16 h = __float2bfloat16(f);
  return *reinterpret_cast<u16*>(&h);
}

// ---------------------------------------------------------------------------
// Kernel 1: convert x -> bf16; transpose weights to (N,K) bf16 layout.
// ---------------------------------------------------------------------------
__global__ __launch_bounds__(256) void prep_kernel(
    const float* __restrict__ x, const float* __restrict__ wqkv,
    const float* __restrict__ wout,
    u16* __restrict__ xb, u16* __restrict__ wqkvT, u16* __restrict__ woutT) {
  int i = blockIdx.x * blockDim.x + threadIdx.x;
  int n = gridDim.x * blockDim.x;
  for (int idx = i; idx < BT_*D_; idx += n)
    xb[idx] = bf16bits(x[idx]);
  for (int idx = i; idx < N3D_*D_; idx += n) {
    int nn = idx >> 9, kk = idx & 511;
    wqkvT[idx] = bf16bits(wqkv[kk * N3D_ + nn]);
  }
  for (int idx = i; idx < D_*D_; idx += n) {
    int nn = idx >> 9, kk = idx & 511;
    woutT[idx] = bf16bits(wout[kk * D_ + nn]);
  }
}

// ---------------------------------------------------------------------------
// GEMM: C[M=8192][N] = A[M][512] * Wt[N][512]^T  (both bf16, K=512, BK=64)
// 128x128 tile, 4 waves, each wave owns a 64x64 quadrant = 4x4 MFMA frags.
// MODE 0: N=1536, epilogue scatters into q (scaled QSCALE), k, v^T bf16 bufs.
// MODE 1: N=512,  epilogue adds bias, multiplies row mask, stores f32.
// ---------------------------------------------------------------------------
template <int MODE>
__global__ __launch_bounds__(256) void gemm_kernel(
    const u16* __restrict__ A, const u16* __restrict__ Wt,
    u16* __restrict__ qbuf, u16* __restrict__ kbuf, u16* __restrict__ vtbuf,
    const float* __restrict__ bias, const float* __restrict__ msk,
    float* __restrict__ out) {
  const int bn = blockIdx.x, bm = blockIdx.y;
  const int tid = threadIdx.x;
  const int w = tid >> 6, l = tid & 63;
  const int wr = w >> 1, wc = w & 1;
  const int lr = l & 15, lg = l >> 4;

  __shared__ char lsA[128 * 128];   // [128 rows][64 bf16]
  __shared__ char lsB[128 * 128];

  f32x4 acc[4][4];
#pragma unroll
  for (int i = 0; i < 4; ++i)
#pragma unroll
    for (int j = 0; j < 4; ++j) acc[i][j] = fzero();

  const long arow0 = (long)bm * 128;
  const long brow0 = (long)bn * 128;
  const char* Ab  = reinterpret_cast<const char*>(A);
  const char* Wb  = reinterpret_cast<const char*>(Wt);

  for (int kt = 0; kt < 8; ++kt) {
#pragma unroll
    for (int s = 0; s < 4; ++s) {
      int u = tid + s * 256;          // 0..1023, 16B units
      int row = u >> 3;
      int cb = (u & 7) << 4;          // byte col within 128B row
      short8 va = *reinterpret_cast<const short8*>(
          Ab + (arow0 + row) * 1024 + kt * 128 + cb);
      *reinterpret_cast<short8*>(lsA + swz(row * 128 + cb)) = va;
      short8 vb = *reinterpret_cast<const short8*>(
          Wb + (brow0 + row) * 1024 + kt * 128 + cb);
      *reinterpret_cast<short8*>(lsB + swz(row * 128 + cb)) = vb;
    }
    __syncthreads();

#pragma unroll
    for (int c = 0; c < 2; ++c) {
      short8 af[4], bfr[4];
#pragma unroll
      for (int mi = 0; mi < 4; ++mi) {
        int row = wr * 64 + mi * 16 + lr;
        af[mi] = *reinterpret_cast<const short8*>(
            lsA + swz(row * 128 + c * 64 + lg * 16));
      }
#pragma unroll
      for (int ni = 0; ni < 4; ++ni) {
        int row = wc * 64 + ni * 16 + lr;
        bfr[ni] = *reinterpret_cast<const short8*>(
            lsB + swz(row * 128 + c * 64 + lg * 16));
      }
#pragma unroll
      for (int mi = 0; mi < 4; ++mi)
#pragma unroll
        for (int ni = 0; ni < 4; ++ni)
          acc[mi][ni] = mfma16(af[mi], bfr[ni], acc[mi][ni]);
    }
    __syncthreads();
  }

  // epilogue: D-frag mapping col=lane&15, row=(lane>>4)*4+reg
#pragma unroll
  for (int mi = 0; mi < 4; ++mi) {
#pragma unroll
    for (int r = 0; r < 4; ++r) {
      int grow = bm * 128 + wr * 64 + mi * 16 + lg * 4 + r;
#pragma unroll
      for (int ni = 0; ni < 4; ++ni) {
        int gcol = bn * 128 + wc * 64 + ni * 16 + lr;
        float v = acc[mi][ni][r];
        if (MODE == 0) {
          int b = grow >> 11, t = grow & (T_ - 1);
          int which = gcol >> 9, w512 = gcol & 511;
          int h = w512 >> 6, d = w512 & 63;
          long bh = (long)(b * H_ + h);
          if (which == 0)       qbuf[(bh * T_ + t) * DH_ + d] = bf16bits(v * QSCALE_F);
          else if (which == 1)  kbuf[(bh * T_ + t) * DH_ + d] = bf16bits(v);
          else                  vtbuf[(bh * DH_ + d) * T_ + t] = bf16bits(v);
        } else {
          float o = (v + bias[gcol]) * msk[grow];
          out[(long)grow * D_ + gcol] = o;
        }
      }
    }
  }
}

// ---------------------------------------------------------------------------
// Flash attention, swapped-QK^T in-register softmax.
// Grid (bh=32, qtslot=32); qt = 31 - qtslot so biggest blocks dispatch first.
// 4 waves/block, 16 q-rows per wave; KV tile 64. Lane owns q-row = lane&15;
// S^T = mfma(K_frag, Q_frag) -> lane holds 16 S values of its own q-row.
// Length-aware: early-exit fully-masked q-tiles, clamp kv loop to valid len.
// T14 async-stage: next K/V tile's global loads issued before compute.
// ---------------------------------------------------------------------------
__global__ __launch_bounds__(256) void attn_kernel(
    const u16* __restrict__ q, const u16* __restrict__ k,
    const u16* __restrict__ vt, const float* __restrict__ msk,
    u16* __restrict__ ao) {
  const int bh = blockIdx.x;              // 0..31
  const int qt = 31 - blockIdx.y;         // biggest first
  const int b = bh >> 3, h = bh & 7;
  const int tid = threadIdx.x;
  const int w = tid >> 6, l = tid & 63;
  const int lr = l & 15, lg = l >> 4;

  const float* mrow = msk + b * T_;

  // number of valid kv tiles (mask is a monotone prefix)
  unsigned long long bal = __ballot((l < 32) ? (mrow[l * 64] != 0.f) : false);
  const int nvalid = __popcll(bal);
  if (qt >= nvalid) return;               // whole q-tile masked: ao*m==0 later
  const int nkv = (qt + 1 < nvalid) ? (qt + 1) : nvalid;

  __shared__ char lsK[64 * 128];
  __shared__ char lsV[64 * 128];
  __shared__ char lsP[4 * 16 * 128];
  char* pbase = lsP + w * (16 * 128);

  const char* kb = reinterpret_cast<const char*>(k)  + (long)bh * T_ * 128;
  const char* vb = reinterpret_cast<const char*>(vt) + (long)bh * DH_ * T_ * 2;
  const char* qb = reinterpret_cast<const char*>(q);

  const int qrow0 = qt * 64 + w * 16;

  // hoist Q fragments (B-operand: col=q-row=lr, k-chunk lg*8)
  short8 qf[2];
#pragma unroll
  for (int c = 0; c < 2; ++c)
    qf[c] = *reinterpret_cast<const short8*>(
        qb + (((long)bh * T_ + qrow0 + lr) * DH_ + c * 32 + lg * 8) * 2);

  const int u0 = tid, u1 = tid + 256;
  const int r0 = u0 >> 3, c0 = (u0 & 7) << 4;
  const int r1 = u1 >> 3, c1 = (u1 & 7) << 4;

  // prefetch tile 0
  short8 rk0 = *reinterpret_cast<const short8*>(kb + r0 * 128 + c0);
  short8 rk1 = *reinterpret_cast<const short8*>(kb + r1 * 128 + c1);
  short8 rv0 = *reinterpret_cast<const short8*>(vb + r0 * (T_*2) + c0);
  short8 rv1 = *reinterpret_cast<const short8*>(vb + r1 * (T_*2) + c1);

  float mrun = -__builtin_inff(), lrun = 0.f;
  f32x4 oacc[4];
#pragma unroll
  for (int g = 0; g < 4; ++g) oacc[g] = fzero();

  for (int kt = 0; kt < nkv; ++kt) {
    if (kt) __syncthreads();              // all waves done reading prev tile
    *reinterpret_cast<short8*>(lsK + swz(r0 * 128 + c0)) = rk0;
    *reinterpret_cast<short8*>(lsK + swz(r1 * 128 + c1)) = rk1;
    *reinterpret_cast<short8*>(lsV + swz(r0 * 128 + c0)) = rv0;
    *reinterpret_cast<short8*>(lsV + swz(r1 * 128 + c1)) = rv1;
    __syncthreads();

    // async-stage next tile (T14): loads in flight across the compute phase
    if (kt + 1 < nkv) {
      rk0 = *reinterpret_cast<const short8*>(kb + ((kt+1)*64 + r0) * 128 + c0);
      rk1 = *reinterpret_cast<const short8*>(kb + ((kt+1)*64 + r1) * 128 + c1);
      rv0 = *reinterpret_cast<const short8*>(vb + r0 * (T_*2) + (kt+1)*128 + c0);
      rv1 = *reinterpret_cast<const short8*>(vb + r1 * (T_*2) + (kt+1)*128 + c1);
    }

    // S^T = K * Q^T: lane holds S[q=lr][k = kt*64 + ni*16 + lg*4 + r]
    f32x4 st[4];
#pragma unroll
    for (int ni = 0; ni < 4; ++ni) {
      short8 kf0 = *reinterpret_cast<const short8*>(
          lsK + swz((ni * 16 + lr) * 128 + lg * 16));
      short8 kf1 = *reinterpret_cast<const short8*>(
          lsK + swz((ni * 16 + lr) * 128 + 64 + lg * 16));
      f32x4 z = fzero();
      z = mfma16(kf0, qf[0], z);
      z = mfma16(kf1, qf[1], z);
      st[ni] = z;
    }

    // masking: only diagonal tile (causal) and length-boundary tile (cols)
    const bool diag = (kt == qt);
    const bool needcm = (mrow[kt * 64 + 63] == 0.f);
    if (diag || needcm) {
#pragma unroll
      for (int ni = 0; ni < 4; ++ni)
#pragma unroll
        for (int r = 0; r < 4; ++r) {
          int jin = ni * 16 + lg * 4 + r;
          bool bad = (diag && jin > w * 16 + lr) ||
                     (needcm && mrow[kt * 64 + jin] == 0.f);
          if (bad) st[ni][r] = -3.402823466e38f;
        }
    }

    // online softmax: lane owns one q-row; reduce across lg (xor 16, 32)
    float pmax = -3.402823466e38f;
#pragma unroll
    for (int ni = 0; ni < 4; ++ni)
#pragma unroll
      for (int r = 0; r < 4; ++r) pmax = fmaxf(pmax, st[ni][r]);
    pmax = fmaxf(pmax, __shfl_xor(pmax, 16));
    pmax = fmaxf(pmax, __shfl_xor(pmax, 32));

    if (!__all(pmax - mrun <= 8.f)) {     // defer-max (T13)
      float newm = fmaxf(mrun, pmax);
      float alpha = fastexp(mrun - newm);
      lrun *= alpha;
      mrun = newm;
#pragma unroll
      for (int rr = 0; rr < 4; ++rr) {
        float a = __shfl(alpha, lg * 4 + rr, 16);
#pragma unroll
        for (int g = 0; g < 4; ++g) oacc[g][rr] *= a;
      }
    }

    float p[4][4];
    float rs = 0.f;
#pragma unroll
    for (int ni = 0; ni < 4; ++ni)
#pragma unroll
      for (int r = 0; r < 4; ++r) {
        float pv = fastexp(st[ni][r] - mrun);
        p[ni][r] = pv;
        rs += pv;
      }
    rs += __shfl_xor(rs, 16);
    rs += __shfl_xor(rs, 32);
    lrun += rs;

    // P -> per-wave LDS (packed bf16x2), row = own q-row lr
#pragma unroll
    for (int ni = 0; ni < 4; ++ni)
#pragma unroll
      for (int rp = 0; rp < 2; ++rp) {
        unsigned lo = bf16bits(p[ni][2 * rp]);
        unsigned hi = bf16bits(p[ni][2 * rp + 1]);
        *reinterpret_cast<unsigned*>(
            pbase + swz(lr * 128 + ni * 32 + lg * 8 + rp * 4)) = lo | (hi << 16);
      }
    asm volatile("s_waitcnt lgkmcnt(0)" ::: "memory");

    // O += P V : A from P-lds (row=q=lr), B from V^T-lds (col=d=lr)
#pragma unroll
    for (int c = 0; c < 2; ++c) {
      short8 pa = *reinterpret_cast<const short8*>(
          pbase + swz(lr * 128 + c * 64 + lg * 16));
#pragma unroll
      for (int g = 0; g < 4; ++g) {
        short8 vf = *reinterpret_cast<const short8*>(
            lsV + swz((g * 16 + lr) * 128 + c * 64 + lg * 16));
        oacc[g] = mfma16(pa, vf, oacc[g]);
      }
    }
  }

  // finalize: O rows q = lg*4+rr, lrun lives at lane lr==q -> shfl broadcast
#pragma unroll
  for (int rr = 0; rr < 4; ++rr) {
    float ls = __shfl(lrun, lg * 4 + rr, 16);
    float inv = 1.0f / ls;
    int t = qrow0 + lg * 4 + rr;
#pragma unroll
    for (int g = 0; g < 4; ++g)
      ao[((long)(b * T_ + t)) * D_ + h * 64 + g * 16 + lr] =
          bf16bits(oacc[g][rr] * inv);
  }
}

// ---------------------------------------------------------------------------
extern "C" void kernel_launch(void* const* d_in, const int* in_sizes, int n_in,
                              void* d_out, int out_size, void* d_ws,
                              size_t ws_size, hipStream_t stream) {
  const float* x    = (const float*)d_in[0];
  const float* msk  = (const float*)d_in[1];   // (B,T,1)
  const float* wqkv = (const float*)d_in[2];   // (512,1536)
  const float* wout = (const float*)d_in[3];   // (512,512)
  const float* bout = (const float*)d_in[4];   // (512,)
  float* out = (float*)d_out;

  char* ws = (char*)d_ws;
  u16* xb    = (u16*)(ws);                     //  8 MB  x bf16 (8192,512)
  u16* wqkvT = (u16*)(ws + 8388608);           //  1.5MB (1536,512)
  u16* woutT = (u16*)(ws + 9961472);           //  0.5MB (512,512)
  u16* qbuf  = (u16*)(ws + 10485760);          //  8 MB  (B,H,T,DH) scaled
  u16* kbuf  = (u16*)(ws + 18874368);          //  8 MB  (B,H,T,DH)
  u16* vtbuf = (u16*)(ws + 27262976);          //  8 MB  (B,H,DH,T)
  u16* ao    = (u16*)(ws + 35651584);          //  8 MB  (B,T,D)

  prep_kernel<<<1024, 256, 0, stream>>>(x, wqkv, wout, xb, wqkvT, woutT);
  gemm_kernel<0><<<dim3(N3D_ / 128, BT_ / 128), 256, 0, stream>>>(
      xb, wqkvT, qbuf, kbuf, vtbuf, nullptr, nullptr, nullptr);
  attn_kernel<<<dim3(B_ * H_, T_ / 64), 256, 0, stream>>>(
      qbuf, kbuf, vtbuf, msk, ao);
  gemm_kernel<1><<<dim3(D_ / 128, BT_ / 128), 256, 0, stream>>>(
      ao, woutT, nullptr, nullptr, nullptr, bout, msk, out);
}